// Round 2
// baseline (676.828 us; speedup 1.0000x reference)
//
#include <hip/hip_runtime.h>
#include <hip/hip_fp16.h>

#define N_S 32
#define N_V 16
#define NB 8
#define HH 64
#define NIR 112
#define ROW 240   // 48 scalar + 64*3 vector output channels
#define MROW 120  // tier-B mix row: 112 fp16 mix + {u0,u1,u2 fp32, sender int}
#define GCAP 64   // tier-B edges staged per gather chunk

typedef _Float16 half8 __attribute__((ext_vector_type(8)));
typedef _Float16 half4v __attribute__((ext_vector_type(4)));
typedef float f32x4 __attribute__((ext_vector_type(4)));

#define H8F(arr, idx) ((float)arr[(idx) >> 3][(idx) & 7])

__device__ __forceinline__ float swishf(float x) {
  return x / (1.f + __expf(-x));
}

struct ChanDesc { int path, off, mixI, i; };

__device__ __forceinline__ void mkDesc(int t, ChanDesc& d) {
  if (t < 32) { d.path = 0; d.off = t; d.mixI = t; d.i = 0; }
  else if (t < 48) { d.path = 1; d.off = 3 * (t - 32); d.mixI = t; d.i = 0; }
  else if (t < ROW) {
    int q = t - 48, c = q / 3, i = q - 3 * c;
    d.mixI = 48 + c;
    if (c < 16) { d.path = 2; d.off = q; d.i = 0; }
    else if (c < 48) { d.path = 3; d.off = c - 16; d.i = i; }
    else { d.path = 4; d.off = 3 * (c - 48); d.i = i; }
  } else { d.path = -1; d.off = 0; d.mixI = 0; d.i = 0; }
}

__device__ __forceinline__ float evalChan(const ChanDesc& d,
                                          const float* __restrict__ srow,
                                          const float* __restrict__ vrow,
                                          float mix, float u0, float u1, float u2) {
  if (d.path < 0) return 0.f;
  if (d.path == 0) return srow[d.off] * mix;
  if (d.path == 2) return vrow[d.off] * mix;
  float uo = d.i == 0 ? u0 : (d.i == 1 ? u1 : u2);
  if (d.path == 3) return srow[d.off] * uo * mix;
  float dd = vrow[d.off] * u0 + vrow[d.off + 1] * u1 + vrow[d.off + 2] * u2;
  if (d.path == 1) return dd * mix;
  return 1.22474487139f * (uo * dd - vrow[d.off + d.i] * 0.33333333333f) * mix;
}

__device__ __forceinline__ float evalChan16(const ChanDesc& d,
                                            const _Float16* __restrict__ srow,
                                            const _Float16* __restrict__ vrow,
                                            float mix, float u0, float u1, float u2) {
  if (d.path == 0) return (float)srow[d.off] * mix;
  if (d.path == 2) return (float)vrow[d.off] * mix;
  float uo = d.i == 0 ? u0 : (d.i == 1 ? u1 : u2);
  if (d.path == 3) return (float)srow[d.off] * uo * mix;
  float dd = (float)vrow[d.off] * u0 + (float)vrow[d.off + 1] * u1 + (float)vrow[d.off + 2] * u2;
  if (d.path == 1) return dd * mix;
  return 1.22474487139f * (uo * dd - (float)vrow[d.off + d.i] * 0.33333333333f) * mix;
}

__device__ __forceinline__ void radialEmb(float x, float y, float z, bool valid,
                                          float* emb, float* u0, float* u1, float* u2) {
  float r2 = x * x + y * y + z * z;
  float r = sqrtf(r2);
  float invr = 1.f / fmaxf(r, 1e-12f);
  *u0 = x * invr; *u1 = y * invr; *u2 = z * invr;
  float env = 0.f;
  if (r < 1.f) {
    float r3 = r * r2;
    float r6 = r3 * r3;
    env = 1.f + r6 * (-28.f + (48.f - 21.f * r) * r);
  }
  float coef = 1.41421356237f * invr * env;
  if (!valid || r == 0.f) coef = 0.f;
  float ph = 3.14159265358979323846f * r;
  float s1 = __sinf(ph), c1 = __cosf(ph);
  float twc = 2.f * c1;
  float sp = 0.f, sc = s1;
#pragma unroll
  for (int n = 0; n < NB; ++n) {  // sin(pi*n*r) via Chebyshev recurrence
    emb[n] = coef * sc;
    float sn = twc * sc - sp;
    sp = sc;
    sc = sn;
  }
}

// ============================ sort ============================

__global__ __launch_bounds__(256) void hist_kernel(const int* __restrict__ rcv,
                                                   int* __restrict__ hist, int E) {
  int e = blockIdx.x * 256 + threadIdx.x;
  if (e < E) atomicAdd(&hist[rcv[e]], 1);
}

__global__ __launch_bounds__(256) void scan1_kernel(const int* __restrict__ hist,
                                                    int* __restrict__ scanTmp,
                                                    int* __restrict__ bsum, int N) {
  __shared__ int sh[256];
  int t = threadIdx.x;
  int i = blockIdx.x * 256 + t;
  sh[t] = (i < N) ? hist[i] : 0;
  __syncthreads();
#pragma unroll
  for (int off = 1; off < 256; off <<= 1) {
    int x = (t >= off) ? sh[t - off] : 0;
    __syncthreads();
    sh[t] += x;
    __syncthreads();
  }
  if (i < N) scanTmp[i] = sh[t];
  if (t == 255) bsum[blockIdx.x] = sh[255];
}

__global__ __launch_bounds__(256) void scan2_kernel(int* __restrict__ bsum, int nb) {
  __shared__ int sh[256];
  int t = threadIdx.x;
  sh[t] = (t < nb) ? bsum[t] : 0;
  __syncthreads();
#pragma unroll
  for (int off = 1; off < 256; off <<= 1) {
    int x = (t >= off) ? sh[t - off] : 0;
    __syncthreads();
    sh[t] += x;
    __syncthreads();
  }
  int excl = (t == 0) ? 0 : sh[t - 1];
  if (t < nb) bsum[t] = excl;
}

__global__ __launch_bounds__(256) void scan3_kernel(const int* __restrict__ scanTmp,
                                                    const int* __restrict__ bsum,
                                                    const int* __restrict__ hist,
                                                    int* __restrict__ offs,
                                                    int* __restrict__ cursor, int N) {
  int i = blockIdx.x * 256 + threadIdx.x;
  if (i < N) {
    int incl = scanTmp[i] + bsum[blockIdx.x];
    offs[i + 1] = incl;
    cursor[i] = incl - hist[i];
    if (i == 0) offs[0] = 0;
  }
}

__global__ __launch_bounds__(256) void reorderInv_kernel(const int* __restrict__ rcv,
                                                         int* __restrict__ cursor,
                                                         int* __restrict__ invPos, int E) {
  int e = blockIdx.x * 256 + threadIdx.x;
  if (e < E) {
    int pos = atomicAdd(&cursor[rcv[e]], 1);
    invPos[e] = pos;
  }
}

// order[pos] = e : sorted edge list (tier A)
__global__ __launch_bounds__(256) void reorderOrd_kernel(const int* __restrict__ rcv,
                                                         int* __restrict__ cursor,
                                                         int* __restrict__ order, int E) {
  int e = blockIdx.x * 256 + threadIdx.x;
  if (e < E) {
    int pos = atomicAdd(&cursor[rcv[e]], 1);
    order[pos] = e;
  }
}

// ==================== prep: weights fp16-T (scales folded) + nodes fp16 ====================

__global__ __launch_bounds__(256) void prep_kernel(const float* __restrict__ W1,
                                                   const float* __restrict__ W2,
                                                   const float* __restrict__ ns,
                                                   const float* __restrict__ nv,
                                                   _Float16* __restrict__ W1T,
                                                   _Float16* __restrict__ W2T,
                                                   _Float16* __restrict__ s16,
                                                   _Float16* __restrict__ v16, int N) {
  int i = blockIdx.x * 256 + threadIdx.x;
  int ts = N * N_S;
  int tv = N * N_V * 3;
  if (i < ts) s16[i] = (_Float16)ns[i];
  else if (i < ts + tv) v16[i - ts] = (_Float16)nv[i - ts];
  else if (i < ts + tv + 4096) {
    int j = i - ts - tv;
    int k = j >> 6, n = j & 63;
    W1T[n * 64 + k] = (_Float16)(W1[k * 64 + n] * 0.125f);
  } else if (i < ts + tv + 4096 + 7168) {
    int j = i - ts - tv - 4096;
    int k = j / 112, n = j - k * 112;
    W2T[n * 64 + k] = (_Float16)(W2[k * 112 + n] * 0.125f);
  }
}

// ==================== tier A: fused MLP + message eval over sorted positions ====================
// Pass k covers sorted positions [P0,P1). Edge identity via order[pos]; message rows
// land densely at msgS[pos-P0] in fp32 (fp16 message storage double-rounds: mix is
// already fp16, and rounding the O(300)-magnitude products again gave 1.75 absmax).
__global__ __launch_bounds__(256, 2) void mlp_msg_pass_kernel(
    const float* __restrict__ vec,
    const float* __restrict__ W0,
    const _Float16* __restrict__ W1T,   // [n=64][k=64], *0.125
    const _Float16* __restrict__ W2T,   // [n=112][k=64], *0.125
    const int* __restrict__ senders,
    const int* __restrict__ order,      // sorted-pos -> edge
    const _Float16* __restrict__ s16,
    const _Float16* __restrict__ v16,
    float* __restrict__ msgS,           // [chunk][240] fp32
    int P0, int P1) {
  __shared__ __align__(16) _Float16 hbuf[4 * 64 * 72];
  const int lane = threadIdx.x & 63;
  const int wave = threadIdx.x >> 6;
  const int gbase = blockIdx.x * 256 + wave * 64;
  _Float16* hb = hbuf + wave * (64 * 72);

  const int m15 = lane & 15;
  const int q = lane >> 4;

  const int pos = P0 + gbase + lane;
  const bool valid = pos < P1;
  float x = 0.f, y = 0.f, z = 0.f;
  int snd = 0;
  if (valid) {
    int e = order[pos];
    const float* vp = vec + 3 * (size_t)e;
    x = vp[0]; y = vp[1]; z = vp[2];
    snd = senders[e];
  }
  float emb[NB], u0, u1, u2;
  radialEmb(x, y, z, valid, emb, &u0, &u1, &u2);

  // ---- phase 1: h1 -> LDS row [edge][64] ----
  for (int kg = 0; kg < 8; ++kg) {
    half8 pk;
#pragma unroll
    for (int kk = 0; kk < 8; ++kk) {
      int k = kg * 8 + kk;
      float a = 0.f;
#pragma unroll
      for (int n = 0; n < NB; ++n) a = fmaf(emb[n], W0[n * HH + k], a);
      pk[kk] = (_Float16)swishf(a * 0.35355339059f);
    }
    *(half8*)(hb + lane * 72 + kg * 8) = pk;
  }

  // ---- sender node rows (fp16), issued early to hide latency behind MFMAs ----
  half8 ss[4], vv[6];
  {
    const _Float16* sp = s16 + (size_t)snd * N_S;
    const _Float16* vp16 = v16 + (size_t)snd * (N_V * 3);
#pragma unroll
    for (int k = 0; k < 4; ++k) ss[k] = *(const half8*)(sp + k * 8);
#pragma unroll
    for (int k = 0; k < 6; ++k) vv[k] = *(const half8*)(vp16 + k * 8);
  }

  // ---- layer 1: MFMA, swish, h2 in place ----
  {
    half8 bW1[4][2];
#pragma unroll
    for (int nt = 0; nt < 4; ++nt)
#pragma unroll
      for (int q2 = 0; q2 < 2; ++q2)
        bW1[nt][q2] = *(const half8*)(W1T + (nt * 16 + m15) * 64 + q2 * 32 + q * 8);
#pragma unroll
    for (int t = 0; t < 4; ++t) {
      half8 a0 = *(const half8*)(hb + (t * 16 + m15) * 72 + q * 8);
      half8 a1 = *(const half8*)(hb + (t * 16 + m15) * 72 + 32 + q * 8);
#pragma unroll
      for (int nt = 0; nt < 4; ++nt) {
        f32x4 d = {0.f, 0.f, 0.f, 0.f};
        d = __builtin_amdgcn_mfma_f32_16x16x32_f16(a0, bW1[nt][0], d, 0, 0, 0);
        d = __builtin_amdgcn_mfma_f32_16x16x32_f16(a1, bW1[nt][1], d, 0, 0, 0);
#pragma unroll
        for (int r = 0; r < 4; ++r)
          hb[(t * 16 + q * 4 + r) * 72 + nt * 16 + m15] = (_Float16)swishf(d[r]);
      }
    }
  }

  // ---- layer 2 A-fragments ----
  half8 A2[4][2];
#pragma unroll
  for (int t = 0; t < 4; ++t)
#pragma unroll
    for (int q2 = 0; q2 < 2; ++q2)
      A2[t][q2] = *(const half8*)(hb + (t * 16 + m15) * 72 + q2 * 32 + q * 8);

  // ---- dot products d[j] = v_j . u ----
  float d16[16];
#pragma unroll
  for (int j = 0; j < 16; ++j)
    d16[j] = H8F(vv, 3 * j) * u0 + H8F(vv, 3 * j + 1) * u1 + H8F(vv, 3 * j + 2) * u2;

  float* orow = msgS + (size_t)(gbase + lane) * ROW;

  // ---- layer 2 half 0 (mix ch 0..63) ----
  for (int nl = 0; nl < 4; ++nl) {
    half8 b0 = *(const half8*)(W2T + (nl * 16 + m15) * 64 + q * 8);
    half8 b1 = *(const half8*)(W2T + (nl * 16 + m15) * 64 + 32 + q * 8);
#pragma unroll
    for (int t = 0; t < 4; ++t) {
      f32x4 d = {0.f, 0.f, 0.f, 0.f};
      d = __builtin_amdgcn_mfma_f32_16x16x32_f16(A2[t][0], b0, d, 0, 0, 0);
      d = __builtin_amdgcn_mfma_f32_16x16x32_f16(A2[t][1], b1, d, 0, 0, 0);
#pragma unroll
      for (int r = 0; r < 4; ++r)
        hb[(t * 16 + q * 4 + r) * 72 + nl * 16 + m15] = (_Float16)d[r];
    }
  }
  half8 m0[8];
#pragma unroll
  for (int k = 0; k < 8; ++k) m0[k] = *(const half8*)(hb + lane * 72 + k * 8);

  // ---- layer 2 half 1 (mix ch 64..111 -> hb cols 0..47); reads above precede writes ----
  for (int nl = 0; nl < 3; ++nl) {
    int ntg = 4 + nl;
    half8 b0 = *(const half8*)(W2T + (ntg * 16 + m15) * 64 + q * 8);
    half8 b1 = *(const half8*)(W2T + (ntg * 16 + m15) * 64 + 32 + q * 8);
#pragma unroll
    for (int t = 0; t < 4; ++t) {
      f32x4 d = {0.f, 0.f, 0.f, 0.f};
      d = __builtin_amdgcn_mfma_f32_16x16x32_f16(A2[t][0], b0, d, 0, 0, 0);
      d = __builtin_amdgcn_mfma_f32_16x16x32_f16(A2[t][1], b1, d, 0, 0, 0);
#pragma unroll
      for (int r = 0; r < 4; ++r)
        hb[(t * 16 + q * 4 + r) * 72 + nl * 16 + m15] = (_Float16)d[r];
    }
  }

  // ---- eval + store message ch 0..95 (needs mix half0 only), fp32 ----
#pragma unroll
  for (int ck = 0; ck < 12; ++ck) {
    f32x4 o0, o1;
#pragma unroll
    for (int jj = 0; jj < 8; ++jj) {
      const int t = ck * 8 + jj;
      float val;
      if (t < 32) {
        val = H8F(m0, t) * H8F(ss, t);
      } else if (t < 48) {
        val = H8F(m0, t) * d16[t - 32];
      } else {
        const int c = (t - 48) / 3;
        val = H8F(m0, 48 + c) * H8F(vv, t - 48);
      }
      if (jj < 4) o0[jj] = val; else o1[jj - 4] = val;
    }
    if (valid) {
      *(f32x4*)(orow + ck * 8) = o0;
      *(f32x4*)(orow + ck * 8 + 4) = o1;
    }
  }

  // ---- read mix half1, eval + store ch 96..239, fp32 ----
  half8 m1[6];
#pragma unroll
  for (int k = 0; k < 6; ++k) m1[k] = *(const half8*)(hb + lane * 72 + k * 8);
#pragma unroll
  for (int ck = 0; ck < 18; ++ck) {
    f32x4 o0, o1;
#pragma unroll
    for (int jj = 0; jj < 8; ++jj) {
      const int t = 96 + ck * 8 + jj;
      const int c = (t - 48) / 3;
      const int i = (t - 48) % 3;
      const float uo = (i == 0) ? u0 : ((i == 1) ? u1 : u2);
      const float m = H8F(m1, c - 16);  // mixI = 48+c, stored at col (48+c)-64
      float val;
      if (c < 48) {
        val = m * H8F(ss, c - 16) * uo;
      } else {
        val = 1.22474487139f * (uo * d16[c - 48] - H8F(vv, t - 192) * 0.33333333333f) * m;
      }
      if (jj < 4) o0[jj] = val; else o1[jj - 4] = val;
    }
    if (valid) {
      *(f32x4*)(orow + 96 + ck * 8) = o0;
      *(f32x4*)(orow + 96 + ck * 8 + 4) = o1;
    }
  }
}

// ==================== tier A gather: pure streaming segmented sum (fp32 rows) ====================
// Handles sorted-position window [P0,P1). A node whose segment starts inside the
// window stores its row fresh; a node whose segment started in an earlier pass
// accumulates (passes are stream-serialized, so plain RMW is safe).
// Empty nodes write their zeros in the first pass.
__global__ __launch_bounds__(256) void gather_stream_kernel(
    const float* __restrict__ msgS,
    const int* __restrict__ offs,
    float* __restrict__ out, int N, int P0, int P1, int isFirst) {
  int wid = blockIdx.x * 4 + (threadIdx.x >> 6);
  int lane = threadIdx.x & 63;
  if (wid >= N) return;
  int s0 = __builtin_amdgcn_readfirstlane(offs[wid]);
  int s1 = __builtin_amdgcn_readfirstlane(offs[wid + 1]);
  const int lo = max(s0, P0);
  const int hi = min(s1, P1);
  const bool ownZero = (s0 == s1) && isFirst;
  if (lo >= hi && !ownZero) return;
  const bool first = s0 >= P0;  // first pass touching this node
  const bool act = lane < 60;

  f32x4 acc = {0.f, 0.f, 0.f, 0.f};
  const float* base = msgS + (size_t)(lo - P0) * ROW + lane * 4;
  const int n = hi - lo;
  int j = 0;
  for (; j + 2 <= n; j += 2) {
    f32x4 va = {0.f, 0.f, 0.f, 0.f}, vb = {0.f, 0.f, 0.f, 0.f};
    if (act) {
      va = *(const f32x4*)(base + (size_t)j * ROW);
      vb = *(const f32x4*)(base + (size_t)(j + 1) * ROW);
    }
    acc += va + vb;
  }
  if (j < n && act) {
    acc += *(const f32x4*)(base + (size_t)j * ROW);
  }
  if (act) {
    float* op = out + (size_t)wid * ROW + lane * 4;
    f32x4 o = {0.f, 0.f, 0.f, 0.f};
    if (!first) o = *(const f32x4*)op;
    o += 0.25f * acc;
    *(f32x4*)op = o;
  }
}

// ==================== tier B: round-7 verified path ====================

__global__ __launch_bounds__(256, 4) void mlp_mfma_sorted_kernel(
    const float* __restrict__ vec,
    const float* __restrict__ W0,
    const _Float16* __restrict__ W1T,
    const _Float16* __restrict__ W2T,
    const int* __restrict__ senders,
    const int* __restrict__ invPos,
    _Float16* __restrict__ mixS,        // [E][MROW]
    int E) {
  __shared__ __align__(16) _Float16 hbuf[4 * 64 * 72];
  const int lane = threadIdx.x & 63;
  const int wave = threadIdx.x >> 6;
  const int gbase = blockIdx.x * 256 + wave * 64;
  _Float16* hb = hbuf + wave * (64 * 72);

  const int m15 = lane & 15;
  const int q = lane >> 4;

  {
    int e = gbase + lane;
    bool valid = e < E;
    float x = 0.f, y = 0.f, z = 0.f;
    int snd = 0;
    if (valid) {
      const float* vp = vec + 3 * (size_t)e;
      x = vp[0]; y = vp[1]; z = vp[2];
      snd = senders[e];
    }
    float emb[NB], u0, u1, u2;
    radialEmb(x, y, z, valid, emb, &u0, &u1, &u2);
    for (int kg = 0; kg < 8; ++kg) {
      half8 pk;
#pragma unroll
      for (int kk = 0; kk < 8; ++kk) {
        int k = kg * 8 + kk;
        float a = 0.f;
#pragma unroll
        for (int n = 0; n < NB; ++n) a = fmaf(emb[n], W0[n * HH + k], a);
        pk[kk] = (_Float16)swishf(a * 0.35355339059f);
      }
      *(half8*)(hb + lane * 72 + kg * 8) = pk;
    }
    float* auxp = (float*)(hb + lane * 72 + 64);
    auxp[0] = u0; auxp[1] = u1; auxp[2] = u2;
    ((int*)auxp)[3] = snd;
  }

  half8 bW1[4][2];
#pragma unroll
  for (int nt = 0; nt < 4; ++nt)
#pragma unroll
    for (int q2 = 0; q2 < 2; ++q2)
      bW1[nt][q2] = *(const half8*)(W1T + (nt * 16 + m15) * 64 + q2 * 32 + q * 8);

#pragma unroll
  for (int t = 0; t < 4; ++t) {
    half8 a0 = *(const half8*)(hb + (t * 16 + m15) * 72 + q * 8);
    half8 a1 = *(const half8*)(hb + (t * 16 + m15) * 72 + 32 + q * 8);
#pragma unroll
    for (int nt = 0; nt < 4; ++nt) {
      f32x4 d = {0.f, 0.f, 0.f, 0.f};
      d = __builtin_amdgcn_mfma_f32_16x16x32_f16(a0, bW1[nt][0], d, 0, 0, 0);
      d = __builtin_amdgcn_mfma_f32_16x16x32_f16(a1, bW1[nt][1], d, 0, 0, 0);
#pragma unroll
      for (int r = 0; r < 4; ++r)
        hb[(t * 16 + q * 4 + r) * 72 + nt * 16 + m15] = (_Float16)swishf(d[r]);
    }
  }

  half8 A2[4][2];
#pragma unroll
  for (int t = 0; t < 4; ++t)
#pragma unroll
    for (int q2 = 0; q2 < 2; ++q2)
      A2[t][q2] = *(const half8*)(hb + (t * 16 + m15) * 72 + q2 * 32 + q * 8);

  for (int nl = 0; nl < 4; ++nl) {
    half8 b0 = *(const half8*)(W2T + (nl * 16 + m15) * 64 + q * 8);
    half8 b1 = *(const half8*)(W2T + (nl * 16 + m15) * 64 + 32 + q * 8);
#pragma unroll
    for (int t = 0; t < 4; ++t) {
      f32x4 d = {0.f, 0.f, 0.f, 0.f};
      d = __builtin_amdgcn_mfma_f32_16x16x32_f16(A2[t][0], b0, d, 0, 0, 0);
      d = __builtin_amdgcn_mfma_f32_16x16x32_f16(A2[t][1], b1, d, 0, 0, 0);
#pragma unroll
      for (int r = 0; r < 4; ++r)
        hb[(t * 16 + q * 4 + r) * 72 + nl * 16 + m15] = (_Float16)d[r];
    }
  }
  for (int it = 0; it < 8; ++it) {
    int c = it * 64 + lane;
    int el = c >> 3, p = c & 7;
    int e = gbase + el;
    half8 v = *(const half8*)(hb + el * 72 + p * 8);
    if (e < E) {
      int pos = invPos[e];
      *(half8*)(mixS + (size_t)pos * MROW + p * 8) = v;
    }
  }

  for (int nl = 0; nl < 3; ++nl) {
    int ntg = 4 + nl;
    half8 b0 = *(const half8*)(W2T + (ntg * 16 + m15) * 64 + q * 8);
    half8 b1 = *(const half8*)(W2T + (ntg * 16 + m15) * 64 + 32 + q * 8);
#pragma unroll
    for (int t = 0; t < 4; ++t) {
      f32x4 d = {0.f, 0.f, 0.f, 0.f};
      d = __builtin_amdgcn_mfma_f32_16x16x32_f16(A2[t][0], b0, d, 0, 0, 0);
      d = __builtin_amdgcn_mfma_f32_16x16x32_f16(A2[t][1], b1, d, 0, 0, 0);
#pragma unroll
      for (int r = 0; r < 4; ++r)
        hb[(t * 16 + q * 4 + r) * 72 + nl * 16 + m15] = (_Float16)d[r];
    }
  }
  for (int it = 0; it < 7; ++it) {
    int c = it * 64 + lane;
    int el = (int)(((unsigned)c * 9363u) >> 16);  // c/7 for c<448
    int p = c - el * 7;
    int e = gbase + el;
    half8 v = *(const half8*)(hb + el * 72 + (p < 6 ? p * 8 : 64));
    if (e < E) {
      int pos = invPos[e];
      *(half8*)(mixS + (size_t)pos * MROW + 64 + p * 8) = v;
    }
  }
}

__global__ __launch_bounds__(256) void gather_lds_kernel(
    const _Float16* __restrict__ mixS,
    const _Float16* __restrict__ s16,
    const _Float16* __restrict__ v16,
    const int* __restrict__ offs,
    float* __restrict__ out, int N) {
  __shared__ __align__(16) _Float16 mixLds[GCAP * MROW];
  __shared__ __align__(16) _Float16 nodeLds[GCAP * 80];

  const int tid = threadIdx.x;
  const int lane = tid & 63;
  const int wave = tid >> 6;
  const int wid0 = blockIdx.x * 4;

  const int e0 = offs[wid0];
  const int e4 = offs[min(wid0 + 4, N)];
  const int wid = wid0 + wave;
  const int sw = offs[min(wid, N)];
  const int ew = offs[min(wid + 1, N)];

  ChanDesc d[4];
#pragma unroll
  for (int tb = 0; tb < 4; ++tb) mkDesc(tb * 64 + lane, d[tb]);

  float acc[4] = {0.f, 0.f, 0.f, 0.f};

  for (int c0 = e0; c0 < e4; c0 += GCAP) {
    const int cnt = min(GCAP, e4 - c0);
    for (int ch = tid; ch < cnt * 15; ch += 256) {
      int row = ch / 15, part = ch - row * 15;
      *(half8*)(mixLds + row * MROW + part * 8) =
          *(const half8*)(mixS + (size_t)(c0 + row) * MROW + part * 8);
    }
    __syncthreads();
    for (int ch = tid; ch < cnt * 10; ch += 256) {
      int row = ch / 10, part = ch - row * 10;
      int snd = ((const int*)(mixLds + row * MROW + 112))[3];
      const _Float16* src = (part < 4)
          ? s16 + (size_t)snd * N_S + part * 8
          : v16 + (size_t)snd * (N_V * 3) + (part - 4) * 8;
      *(half8*)(nodeLds + row * 80 + (part < 4 ? part * 8 : 32 + (part - 4) * 8)) =
          *(const half8*)src;
    }
    __syncthreads();
    const int jlo = max(sw - c0, 0);
    const int jhi = min(ew - c0, cnt);
    for (int j = jlo; j < jhi; ++j) {
      const _Float16* row = mixLds + j * MROW;
      const float* aux = (const float*)(row + 112);
      float u0 = aux[0], u1 = aux[1], u2 = aux[2];
      const _Float16* srow = nodeLds + j * 80;
      const _Float16* vrow = srow + 32;
#pragma unroll
      for (int tb = 0; tb < 4; ++tb) {
        if (d[tb].path >= 0) {
          float m = (float)row[d[tb].mixI];
          acc[tb] += evalChan16(d[tb], srow, vrow, m, u0, u1, u2);
        }
      }
    }
    __syncthreads();
  }

  if (wid < N) {
    float* orow = out + (size_t)wid * ROW;
#pragma unroll
    for (int tb = 0; tb < 4; ++tb) {
      int t = tb * 64 + lane;
      if (t < ROW) orow[t] = 0.25f * acc[tb];
    }
  }
}

// ==================== tier D fallback: atomic edge kernel ====================

__global__ __launch_bounds__(64) void edge_kernel(
    const float* __restrict__ vec,
    const float* __restrict__ nodes_s,
    const float* __restrict__ nodes_v,
    const int* __restrict__ senders,
    const int* __restrict__ receivers,
    const float* __restrict__ W0f,
    const float* __restrict__ W1f,
    const float* __restrict__ W2f,
    float* __restrict__ out, int E) {
  __shared__ float hLds[HH * 64];
  __shared__ float uLds[64 * 3];
  __shared__ int sLds[64];
  __shared__ int rLds[64];
  __half* mixLds = reinterpret_cast<__half*>(hLds);

  const int lane = threadIdx.x;
  const int base = blockIdx.x * 64;
  const int eg = base + lane;
  const bool valid = eg < E;

  float emb[NB];
  {
    float x = 0.f, y = 0.f, z = 0.f;
    int snd = 0, rcv = 0;
    if (valid) {
      const float* vp = vec + 3 * (size_t)eg;
      x = vp[0]; y = vp[1]; z = vp[2];
      snd = senders[eg];
      rcv = receivers[eg];
    }
    float u0, u1, u2;
    radialEmb(x, y, z, valid, emb, &u0, &u1, &u2);
    uLds[lane * 3 + 0] = u0;
    uLds[lane * 3 + 1] = u1;
    uLds[lane * 3 + 2] = u2;
    sLds[lane] = snd;
    rLds[lane] = rcv;
  }

  for (int j0 = 0; j0 < HH; j0 += 8) {
    float a[8];
#pragma unroll
    for (int jj = 0; jj < 8; ++jj) a[jj] = 0.f;
#pragma unroll
    for (int k = 0; k < NB; ++k) {
      const float* wrow = W0f + k * HH + j0;
      float ek = emb[k];
#pragma unroll
      for (int jj = 0; jj < 8; ++jj) a[jj] = fmaf(ek, wrow[jj], a[jj]);
    }
#pragma unroll
    for (int jj = 0; jj < 8; ++jj)
      hLds[(j0 + jj) * 64 + lane] = swishf(a[jj] * 0.35355339059f);
  }
  __syncthreads();

  float h2[HH];
#pragma unroll
  for (int j = 0; j < HH; ++j) h2[j] = 0.f;
  for (int k = 0; k < HH; ++k) {
    float hk = hLds[k * 64 + lane];
    const float* wrow = W1f + k * HH;
#pragma unroll
    for (int j = 0; j < HH; ++j) h2[j] = fmaf(hk, wrow[j], h2[j]);
  }
#pragma unroll
  for (int j = 0; j < HH; ++j) h2[j] = swishf(h2[j] * 0.125f);
  __syncthreads();

  for (int m0 = 0; m0 < NIR; m0 += 4) {
    float a0 = 0.f, a1 = 0.f, a2 = 0.f, a3 = 0.f;
#pragma unroll
    for (int k = 0; k < HH; ++k) {
      const float* wrow = W2f + k * NIR + m0;
      float hk = h2[k];
      a0 = fmaf(hk, wrow[0], a0);
      a1 = fmaf(hk, wrow[1], a1);
      a2 = fmaf(hk, wrow[2], a2);
      a3 = fmaf(hk, wrow[3], a3);
    }
    mixLds[lane * NIR + m0 + 0] = __float2half_rn(a0 * 0.125f);
    mixLds[lane * NIR + m0 + 1] = __float2half_rn(a1 * 0.125f);
    mixLds[lane * NIR + m0 + 2] = __float2half_rn(a2 * 0.125f);
    mixLds[lane * NIR + m0 + 3] = __float2half_rn(a3 * 0.125f);
  }
  __syncthreads();

  ChanDesc d[4];
#pragma unroll
  for (int tb = 0; tb < 4; ++tb) mkDesc(tb * 64 + lane, d[tb]);

  const int cnt = min(64, E - base);
  for (int e = 0; e < cnt; ++e) {
    int snd = sLds[e], rcv = rLds[e];
    float u0 = uLds[e * 3 + 0], u1 = uLds[e * 3 + 1], u2 = uLds[e * 3 + 2];
    const float* srow = nodes_s + (size_t)snd * N_S;
    const float* vrow = nodes_v + (size_t)snd * (N_V * 3);
    const __half* mrow = mixLds + e * NIR;
    float* orow = out + (size_t)rcv * ROW;
#pragma unroll
    for (int tb = 0; tb < 4; ++tb) {
      if (d[tb].path >= 0) {
        float m = __half2float(mrow[d[tb].mixI]);
        float val = evalChan(d[tb], srow, vrow, m, u0, u1, u2);
        unsafeAtomicAdd(orow + tb * 64 + lane, 0.25f * val);
      }
    }
  }
}

// ===============================================================================

extern "C" void kernel_launch(void* const* d_in, const int* in_sizes, int n_in,
                              void* d_out, int out_size, void* d_ws, size_t ws_size,
                              hipStream_t stream) {
  const float* vec = (const float*)d_in[0];
  const float* ns = (const float*)d_in[1];
  const float* nv = (const float*)d_in[2];
  const float* w0 = (const float*)d_in[3];
  const float* w1 = (const float*)d_in[4];
  const float* w2 = (const float*)d_in[5];
  const int* snd = (const int*)d_in[6];
  const int* rcv = (const int*)d_in[7];
  float* out = (float*)d_out;

  const int E = in_sizes[6];
  const int N = in_sizes[1] / N_S;
  const int nb = (N + 255) / 256;
  const int eb = (E + 255) / 256;
  const int prepElems = N * (N_S + N_V * 3) + 4096 + 7168;

  // ---- tier A: multi-pass fused message materialization + streaming gather (fp32 rows) ----
  // Pick the smallest pass count P whose chunk buffer fits the workspace.
  for (int P = 1; P <= 16; ++P) {
    const size_t chunk = ((size_t)E + P - 1) / (size_t)P;  // rows per pass
    char* p = (char*)d_ws;
    float* msgS = (float*)p;        p += chunk * ROW * sizeof(float);
    int* hist = (int*)p;            p += (size_t)N * 4;
    int* scanTmp = (int*)p;         p += (size_t)N * 4;
    int* offs = (int*)p;            p += ((size_t)N + 1) * 4;
    int* cursor = (int*)p;          p += (size_t)N * 4;
    int* bsum = (int*)p;            p += 256 * 4;
    int* order = (int*)p;           p += (size_t)E * 4;
    p = (char*)(((uintptr_t)p + 15) & ~(uintptr_t)15);
    _Float16* W1T = (_Float16*)p;   p += 4096 * sizeof(_Float16);
    _Float16* W2T = (_Float16*)p;   p += 7168 * sizeof(_Float16);
    _Float16* s16 = (_Float16*)p;   p += (size_t)N * N_S * sizeof(_Float16);
    _Float16* v16 = (_Float16*)p;   p += (size_t)N * N_V * 3 * sizeof(_Float16);
    size_t need = (size_t)(p - (char*)d_ws);
    if (need > ws_size || nb > 256) continue;

    hipMemsetAsync(hist, 0, (size_t)N * 4, stream);
    hist_kernel<<<eb, 256, 0, stream>>>(rcv, hist, E);
    scan1_kernel<<<nb, 256, 0, stream>>>(hist, scanTmp, bsum, N);
    scan2_kernel<<<1, 256, 0, stream>>>(bsum, nb);
    scan3_kernel<<<nb, 256, 0, stream>>>(scanTmp, bsum, hist, offs, cursor, N);
    reorderOrd_kernel<<<eb, 256, 0, stream>>>(rcv, cursor, order, E);
    prep_kernel<<<(prepElems + 255) / 256, 256, 0, stream>>>(w1, w2, ns, nv, W1T, W2T, s16, v16, N);

    for (int k = 0; k < P; ++k) {
      const int P0 = (int)((size_t)k * chunk);
      if (P0 >= E) break;
      const int P1 = (int)min((size_t)E, (size_t)P0 + chunk);
      const int cnt = P1 - P0;
      mlp_msg_pass_kernel<<<(cnt + 255) / 256, 256, 0, stream>>>(
          vec, w0, W1T, W2T, snd, order, s16, v16, msgS, P0, P1);
      gather_stream_kernel<<<(N + 3) / 4, 256, 0, stream>>>(
          msgS, offs, out, N, P0, P1, k == 0 ? 1 : 0);
    }
    return;
  }

  // ---- tier B: round-7 verified path ----
  {
    char* p = (char*)d_ws;
    _Float16* mixS = (_Float16*)p;  p += (size_t)E * MROW * sizeof(_Float16);
    int* hist = (int*)p;            p += (size_t)N * 4;
    int* scanTmp = (int*)p;         p += (size_t)N * 4;
    int* offs = (int*)p;            p += ((size_t)N + 1) * 4;
    int* cursor = (int*)p;          p += (size_t)N * 4;
    int* bsum = (int*)p;            p += 256 * 4;
    int* invPos = (int*)p;          p += (size_t)E * 4;
    p = (char*)(((uintptr_t)p + 15) & ~(uintptr_t)15);
    _Float16* W1T = (_Float16*)p;   p += 4096 * sizeof(_Float16);
    _Float16* W2T = (_Float16*)p;   p += 7168 * sizeof(_Float16);
    _Float16* s16 = (_Float16*)p;   p += (size_t)N * N_S * sizeof(_Float16);
    _Float16* v16 = (_Float16*)p;   p += (size_t)N * N_V * 3 * sizeof(_Float16);
    size_t needB = (size_t)(p - (char*)d_ws);

    if (needB <= ws_size && nb <= 256) {
      hipMemsetAsync(hist, 0, (size_t)N * 4, stream);
      hist_kernel<<<eb, 256, 0, stream>>>(rcv, hist, E);
      scan1_kernel<<<nb, 256, 0, stream>>>(hist, scanTmp, bsum, N);
      scan2_kernel<<<1, 256, 0, stream>>>(bsum, nb);
      scan3_kernel<<<nb, 256, 0, stream>>>(scanTmp, bsum, hist, offs, cursor, N);
      reorderInv_kernel<<<eb, 256, 0, stream>>>(rcv, cursor, invPos, E);
      prep_kernel<<<(prepElems + 255) / 256, 256, 0, stream>>>(w1, w2, ns, nv, W1T, W2T, s16, v16, N);
      mlp_mfma_sorted_kernel<<<eb, 256, 0, stream>>>(vec, w0, W1T, W2T, snd, invPos, mixS, E);
      gather_lds_kernel<<<(N + 3) / 4, 256, 0, stream>>>(mixS, s16, v16, offs, out, N);
      return;
    }
  }

  // ---- tier D: atomic fallback ----
  hipMemsetAsync(d_out, 0, (size_t)out_size * sizeof(float), stream);
  edge_kernel<<<(E + 63) / 64, 64, 0, stream>>>(vec, ns, nv, snd, rcv, w0, w1, w2, out, E);
}